// Round 2
// baseline (4768.053 us; speedup 1.0000x reference)
//
#include <hip/hip_runtime.h>
#include <hip/hip_fp16.h>

#define DEVINL __device__ __forceinline__

static constexpr int Bn = 2048;
static constexpr int Sn = 256;
static constexpr long long BSn = (long long)Bn * Sn;  // 524288

typedef _Float16 h2v __attribute__((ext_vector_type(2)));

DEVINL float dot2(unsigned int a, unsigned int b, float c) {
#if __has_builtin(__builtin_amdgcn_fdot2)
    return __builtin_amdgcn_fdot2(__builtin_bit_cast(h2v, a), __builtin_bit_cast(h2v, b), c, false);
#else
    __half2 ha = __builtin_bit_cast(__half2, a);
    __half2 hb = __builtin_bit_cast(__half2, b);
    return c + __low2float(ha) * __low2float(hb) + __high2float(ha) * __high2float(hb);
#endif
}
DEVINL unsigned int packh2(float a, float b) {
    __half2 h = __floats2half2_rn(a, b);
    return __builtin_bit_cast(unsigned int, h);
}
DEVINL float sigmoidf_(float x) { return 1.0f / (1.0f + __expf(-x)); }
DEVINL float tanhf_(float x) { return 2.0f / (1.0f + __expf(-2.0f * x)) - 1.0f; }

// s_tile u32-offset map (weights overlay; row_tile overwrites them after phase 0)
enum {
    O_PE1 = 0,        // [64][12]  pe_w1^T pairs (21 pad 24)
    O_PE2 = 768,      // [64][32]  pe_w2^T pairs
    O_EE1 = 2816,     // [32][8]   ee_w1^T pairs (13 pad 16)
    O_EE2 = 3072,     // [16][16]  ee_w2^T pairs
    O_CB1 = 3328,     // [128][32] cb_w1^T pairs (63 pad 64)
    O_CB2 = 7424,     // [64][64]  cb_w2^T pairs
    O_BIAS = 11520    // 400 floats: pe_b1(64) pe_b2(64) ee_b1(32) ee_b2(16) cb_b1(128) cb_b2(64) role(32)
};

DEVINL void head_emit(int b, int s, int grp, int u,
                      const unsigned int* s_h32, const unsigned int* s_hw,
                      const float* s_hb, float* __restrict__ out)
{
    const int half = u >> 5;
    const int sub = u & 31;
    float p = dot2(s_h32[sub], s_hw[(grp - 1) * 64 + half * 32 + sub], 0.f);
    p += __shfl_xor(p, 1); p += __shfl_xor(p, 2); p += __shfl_xor(p, 4);
    p += __shfl_xor(p, 8); p += __shfl_xor(p, 16);
    long long row = (long long)b * Sn + s;
    if (sub == 0) {
        if (grp == 1) {
            if (half == 0) out[row] = sigmoidf_(p + s_hb[0]);
            else           out[BSn + row] = tanhf_(p + s_hb[1]);
        } else if (grp == 2) {
            out[4 * BSn + 2 * row + half] = p + s_hb[2 + half];
        } else {
            out[6 * BSn + 2 * row + half] = p + s_hb[4 + half];
        }
    }
    if (grp == 1 && u == 1) {
        out[2 * BSn + 2 * row] = s_hb[6];
        out[2 * BSn + 2 * row + 1] = s_hb[7];
    }
}

__global__ __launch_bounds__(256, 2) void k_fused(
    const float* __restrict__ self_obs, const float* __restrict__ tm_obs,
    const float* __restrict__ en_obs, const float* __restrict__ cp_obs,
    const int* __restrict__ role_ids,
    const float* __restrict__ pe_w1, const float* __restrict__ pe_b1,
    const float* __restrict__ pe_w2, const float* __restrict__ pe_b2,
    const float* __restrict__ role_emb,
    const float* __restrict__ ee_w1, const float* __restrict__ ee_b1,
    const float* __restrict__ ee_w2, const float* __restrict__ ee_b2,
    const float* __restrict__ cb_w1, const float* __restrict__ cb_b1,
    const float* __restrict__ cb_w2, const float* __restrict__ cb_b2,
    const float* __restrict__ ih_w, const float* __restrict__ ih_b,
    const float* __restrict__ hh_w, const float* __restrict__ hh_b,
    const float* __restrict__ th_w, const float* __restrict__ th_b,
    const float* __restrict__ an_w, const float* __restrict__ an_b,
    const float* __restrict__ sh_w, const float* __restrict__ sh_b,
    const float* __restrict__ bo_w, const float* __restrict__ bo_b,
    const float* __restrict__ logstd, float* __restrict__ out)
{
    __shared__ __align__(16) unsigned int s_tile[Sn * 64];  // 64 KB: weights, then row tile
    __shared__ __align__(8) __half s_h[64];
    __shared__ float s_g[192];
    __shared__ unsigned int s_hw[192];
    __shared__ float s_hb[8];

    const int t = threadIdx.x;
    const int b = blockIdx.x;

    // ---------------- weight staging (f32 -> f16 pairs, transposed+padded) ----------------
    for (int i = t; i < 768; i += 256) {
        int o = i / 12, m = i % 12, k0 = 2 * m, k1 = k0 + 1;
        float a = (k0 < 21) ? pe_w1[k0 * 64 + o] : 0.f;
        float c = (k1 < 21) ? pe_w1[k1 * 64 + o] : 0.f;
        s_tile[O_PE1 + i] = packh2(a, c);
    }
    for (int i = t; i < 2048; i += 256) {
        int o = i >> 5, m = i & 31;
        s_tile[O_PE2 + i] = packh2(pe_w2[(2 * m) * 64 + o], pe_w2[(2 * m + 1) * 64 + o]);
    }
    if (t < 256) {
        int i = t;  // 256 elems, one pass
        int o = i >> 3, m = i & 7, k0 = 2 * m, k1 = k0 + 1;
        float a = (k0 < 13) ? ee_w1[k0 * 32 + o] : 0.f;
        float c = (k1 < 13) ? ee_w1[k1 * 32 + o] : 0.f;
        s_tile[O_EE1 + i] = packh2(a, c);
    }
    if (t < 256) {
        int i = t;
        int o = i >> 4, m = i & 15;
        s_tile[O_EE2 + i] = packh2(ee_w2[(2 * m) * 16 + o], ee_w2[(2 * m + 1) * 16 + o]);
    }
    for (int i = t; i < 4096; i += 256) {
        int o = i >> 5, m = i & 31, k0 = 2 * m, k1 = k0 + 1;
        float a = (k0 < 63) ? cb_w1[k0 * 128 + o] : 0.f;
        float c = (k1 < 63) ? cb_w1[k1 * 128 + o] : 0.f;
        s_tile[O_CB1 + i] = packh2(a, c);
    }
    for (int i = t; i < 4096; i += 256) {
        int o = i >> 6, m = i & 63;
        s_tile[O_CB2 + i] = packh2(cb_w2[(2 * m) * 64 + o], cb_w2[(2 * m + 1) * 64 + o]);
    }
    float* bias = (float*)(s_tile + O_BIAS);
    if (t < 64) bias[t] = pe_b1[t];
    if (t < 64) bias[64 + t] = pe_b2[t];
    if (t < 32) bias[128 + t] = ee_b1[t];
    if (t < 16) bias[160 + t] = ee_b2[t];
    if (t < 128) bias[176 + t] = cb_b1[t];
    if (t < 64) bias[304 + t] = cb_b2[t];
    if (t < 32) bias[368 + t] = role_emb[t];
    // head weights (persistent tail region)
    if (t < 32)        s_hw[t]        = packh2(th_w[2 * t], th_w[2 * t + 1]);
    else if (t < 64)  { int m = t - 32;  s_hw[32 + m]  = packh2(an_w[2 * m], an_w[2 * m + 1]); }
    else if (t < 96)  { int m = t - 64;  s_hw[64 + m]  = packh2(sh_w[4 * m], sh_w[4 * m + 2]); }
    else if (t < 128) { int m = t - 96;  s_hw[96 + m]  = packh2(sh_w[4 * m + 1], sh_w[4 * m + 3]); }
    else if (t < 160) { int m = t - 128; s_hw[128 + m] = packh2(bo_w[4 * m], bo_w[4 * m + 2]); }
    else if (t < 192) { int m = t - 160; s_hw[160 + m] = packh2(bo_w[4 * m + 1], bo_w[4 * m + 3]); }
    if (t == 0) {
        s_hb[0] = th_b[0]; s_hb[1] = an_b[0];
        s_hb[2] = sh_b[0]; s_hb[3] = sh_b[1];
        s_hb[4] = bo_b[0]; s_hb[5] = bo_b[1];
        s_hb[6] = fmaxf(__expf(logstd[0]), 0.05f);
        s_hb[7] = fmaxf(__expf(logstd[1]), 0.05f);
    }
    if (t < 64) s_h[t] = __float2half(0.f);
    __syncthreads();

    // ---------------- phase 0: encoders, thread t handles step s=t ----------------
    {
        const long long row = (long long)b * Sn + t;
        float sv[15];
        {
            const float* sp = self_obs + row * 15;
            #pragma unroll
            for (int k = 0; k < 15; k++) sv[k] = sp[k];
        }
        unsigned int inp[12];
        {
            float cpv[6];
            const float* cp = cp_obs + row * 6;
            #pragma unroll
            for (int k = 0; k < 6; k++) cpv[k] = cp[k];
            #pragma unroll
            for (int m = 0; m < 12; m++) {
                int k0 = 2 * m, k1 = k0 + 1;
                float a = (k0 < 15) ? sv[k0] : ((k0 < 21) ? cpv[k0 - 15] : 0.f);
                float c = (k1 < 15) ? sv[k1] : ((k1 < 21) ? cpv[k1 - 15] : 0.f);
                inp[m] = packh2(a, c);
            }
        }
        // pilot L1 (21->64 relu)
        unsigned int r1p[32];
        #pragma unroll
        for (int o2 = 0; o2 < 32; o2++) {
            float a0 = bias[2 * o2], a1 = bias[2 * o2 + 1];
            const unsigned int* w0 = s_tile + O_PE1 + (2 * o2) * 12;
            #pragma unroll
            for (int m = 0; m < 12; m++) { a0 = dot2(inp[m], w0[m], a0); a1 = dot2(inp[m], w0[12 + m], a1); }
            r1p[o2] = packh2(fmaxf(a0, 0.f), fmaxf(a1, 0.f));
        }
        // pilot L2 (64->64 relu) -> res[0..31]
        unsigned int res[64];
        #pragma unroll
        for (int o2 = 0; o2 < 32; o2++) {
            float a0 = bias[64 + 2 * o2], a1 = bias[64 + 2 * o2 + 1];
            const unsigned int* w0 = s_tile + O_PE2 + (2 * o2) * 32;
            #pragma unroll
            for (int m = 0; m < 32; m++) { a0 = dot2(r1p[m], w0[m], a0); a1 = dot2(r1p[m], w0[32 + m], a1); }
            res[o2] = packh2(fmaxf(a0, 0.f), fmaxf(a1, 0.f));
        }
        // entity encoders: teammate -> lat[0..15], enemy max -> lat[16..31]
        float lat[32];
        {
            const float* xp = tm_obs + row * 13;
            unsigned int xpr[8];
            #pragma unroll
            for (int m = 0; m < 8; m++) {
                int k0 = 2 * m, k1 = k0 + 1;
                xpr[m] = packh2((k0 < 13) ? xp[k0] : 0.f, (k1 < 13) ? xp[k1] : 0.f);
            }
            unsigned int e1[16];
            #pragma unroll
            for (int o2 = 0; o2 < 16; o2++) {
                float a0 = bias[128 + 2 * o2], a1 = bias[128 + 2 * o2 + 1];
                const unsigned int* w0 = s_tile + O_EE1 + (2 * o2) * 8;
                #pragma unroll
                for (int m = 0; m < 8; m++) { a0 = dot2(xpr[m], w0[m], a0); a1 = dot2(xpr[m], w0[8 + m], a1); }
                e1[o2] = packh2(fmaxf(a0, 0.f), fmaxf(a1, 0.f));
            }
            #pragma unroll
            for (int o = 0; o < 16; o++) {
                float a0 = bias[160 + o];
                const unsigned int* w0 = s_tile + O_EE2 + o * 16;
                #pragma unroll
                for (int m = 0; m < 16; m++) a0 = dot2(e1[m], w0[m], a0);
                lat[o] = a0;  // no relu on L2
            }
        }
        #pragma unroll 1
        for (int e = 0; e < 2; e++) {
            const float* xp = en_obs + row * 26 + e * 13;
            unsigned int xpr[8];
            #pragma unroll
            for (int m = 0; m < 8; m++) {
                int k0 = 2 * m, k1 = k0 + 1;
                xpr[m] = packh2((k0 < 13) ? xp[k0] : 0.f, (k1 < 13) ? xp[k1] : 0.f);
            }
            unsigned int e1[16];
            #pragma unroll
            for (int o2 = 0; o2 < 16; o2++) {
                float a0 = bias[128 + 2 * o2], a1 = bias[128 + 2 * o2 + 1];
                const unsigned int* w0 = s_tile + O_EE1 + (2 * o2) * 8;
                #pragma unroll
                for (int m = 0; m < 8; m++) { a0 = dot2(xpr[m], w0[m], a0); a1 = dot2(xpr[m], w0[8 + m], a1); }
                e1[o2] = packh2(fmaxf(a0, 0.f), fmaxf(a1, 0.f));
            }
            #pragma unroll
            for (int o = 0; o < 16; o++) {
                float a0 = bias[160 + o];
                const unsigned int* w0 = s_tile + O_EE2 + o * 16;
                #pragma unroll
                for (int m = 0; m < 16; m++) a0 = dot2(e1[m], w0[m], a0);
                lat[16 + o] = (e == 0) ? a0 : fmaxf(lat[16 + o], a0);
            }
        }
        // command input pack: sv(15) | lat[0..15] | lat[16..31] | role(16) = 63 (pad 64)
        const int rid = role_ids[row];
        const float* rvec = bias + 368 + rid * 16;
        unsigned int cpp[32];
        #pragma unroll
        for (int m = 0; m < 32; m++) {
            int k0 = 2 * m, k1 = k0 + 1;
            float a = (k0 < 15) ? sv[k0] : (k0 < 31) ? lat[k0 - 15] : (k0 < 47) ? lat[16 + k0 - 31] : rvec[k0 - 47];
            float c = (k1 < 15) ? sv[k1] : (k1 < 31) ? lat[k1 - 15] : (k1 < 47) ? lat[16 + k1 - 31]
                                                                   : (k1 < 63) ? rvec[k1 - 47] : 0.f;
            cpp[m] = packh2(a, c);
        }
        // cmd L1 (63->128 relu)
        unsigned int c1[64];
        #pragma unroll
        for (int o2 = 0; o2 < 64; o2++) {
            float a0 = bias[176 + 2 * o2], a1 = bias[176 + 2 * o2 + 1];
            const unsigned int* w0 = s_tile + O_CB1 + (2 * o2) * 32;
            #pragma unroll
            for (int m = 0; m < 32; m++) { a0 = dot2(cpp[m], w0[m], a0); a1 = dot2(cpp[m], w0[32 + m], a1); }
            c1[o2] = packh2(fmaxf(a0, 0.f), fmaxf(a1, 0.f));
        }
        // cmd L2 (128->64 relu) -> res[32..63]
        #pragma unroll
        for (int o2 = 0; o2 < 32; o2++) {
            float a0 = bias[304 + 2 * o2], a1 = bias[304 + 2 * o2 + 1];
            const unsigned int* w0 = s_tile + O_CB2 + (2 * o2) * 64;
            #pragma unroll
            for (int m = 0; m < 64; m++) { a0 = dot2(c1[m], w0[m], a0); a1 = dot2(c1[m], w0[64 + m], a1); }
            res[32 + o2] = packh2(fmaxf(a0, 0.f), fmaxf(a1, 0.f));
        }
        __syncthreads();  // all phase-0 reads of weights done
        unsigned int* rt = s_tile + t * 64;
        #pragma unroll
        for (int m = 0; m < 64; m++) rt[m] = res[m];  // row tile overwrites weights
    }

    // LSTM weight columns into registers (f16 pairs)
    unsigned int wih[64], whh[32];
    #pragma unroll
    for (int m = 0; m < 64; m++) wih[m] = packh2(ih_w[(2 * m) * 256 + t], ih_w[(2 * m + 1) * 256 + t]);
    #pragma unroll
    for (int m = 0; m < 32; m++) whh[m] = packh2(hh_w[(2 * m) * 256 + t], hh_w[(2 * m + 1) * 256 + t]);
    const float bias_t = ih_b[t] + hh_b[t];
    __syncthreads();  // row tile ready

    // ---------------- LSTM over S ----------------
    const int grp = t >> 6;
    const int u = t & 63;
    const unsigned int* s_h32 = (const unsigned int*)s_h;
    float c = 0.f, h = 0.f, i_act = 0.f;
    #pragma unroll 1
    for (int s = 0; s < Sn; s++) {
        float acc = bias_t;
        const unsigned int* rt = s_tile + s * 64;
        #pragma unroll
        for (int m = 0; m < 64; m++) acc = dot2(rt[m], wih[m], acc);
        #pragma unroll
        for (int m = 0; m < 32; m++) acc = dot2(s_h32[m], whh[m], acc);
        float act = (grp == 2) ? tanhf_(acc) : sigmoidf_(acc);
        if (grp > 0 && s > 0) head_emit(b, s - 1, grp, u, s_h32, s_hw, s_hb, out);
        if (grp == 0) i_act = act; else s_g[(grp - 1) * 64 + u] = act;
        __syncthreads();
        if (grp == 0) {
            float f_ = s_g[u], g_ = s_g[64 + u], o_ = s_g[128 + u];
            c = f_ * c + i_act * g_;
            h = o_ * tanhf_(c);
            s_h[u] = __float2half(h);
        }
        __syncthreads();
    }
    if (grp > 0) head_emit(b, Sn - 1, grp, u, s_h32, s_hw, s_hb, out);
    if (grp == 0) {
        float* hn = out + 8 * BSn;
        float* cn = hn + (long long)Bn * 64;
        hn[(long long)b * 64 + u] = h;
        cn[(long long)b * 64 + u] = c;
    }
}

extern "C" void kernel_launch(void* const* d_in, const int* in_sizes, int n_in,
                              void* d_out, int out_size, void* d_ws, size_t ws_size,
                              hipStream_t stream)
{
    (void)in_sizes; (void)n_in; (void)out_size; (void)d_ws; (void)ws_size;
    k_fused<<<Bn, 256, 0, stream>>>(
        (const float*)d_in[0], (const float*)d_in[1], (const float*)d_in[2],
        (const float*)d_in[3], (const int*)d_in[4],
        (const float*)d_in[5], (const float*)d_in[6], (const float*)d_in[7], (const float*)d_in[8],
        (const float*)d_in[9],
        (const float*)d_in[10], (const float*)d_in[11], (const float*)d_in[12], (const float*)d_in[13],
        (const float*)d_in[14], (const float*)d_in[15], (const float*)d_in[16], (const float*)d_in[17],
        (const float*)d_in[18], (const float*)d_in[19], (const float*)d_in[20], (const float*)d_in[21],
        (const float*)d_in[22], (const float*)d_in[23], (const float*)d_in[24], (const float*)d_in[25],
        (const float*)d_in[26], (const float*)d_in[27], (const float*)d_in[28], (const float*)d_in[29],
        (const float*)d_in[30], (float*)d_out);
}

// Round 3
// 1453.615 us; speedup vs baseline: 3.2801x; 3.2801x over previous
//
#include <hip/hip_runtime.h>
#include <hip/hip_fp16.h>

#define DEVINL __device__ __forceinline__

static constexpr int Bn = 2048;
static constexpr int Sn = 256;
static constexpr long long BSn = (long long)Bn * Sn;  // 524288

typedef _Float16 h2v __attribute__((ext_vector_type(2)));

DEVINL float dot2(unsigned int a, unsigned int b, float c) {
#if __has_builtin(__builtin_amdgcn_fdot2)
    return __builtin_amdgcn_fdot2(__builtin_bit_cast(h2v, a), __builtin_bit_cast(h2v, b), c, false);
#else
    __half2 ha = __builtin_bit_cast(__half2, a);
    __half2 hb = __builtin_bit_cast(__half2, b);
    return c + __low2float(ha) * __low2float(hb) + __high2float(ha) * __high2float(hb);
#endif
}
DEVINL unsigned int packh2(float a, float b) {
    __half2 h = __floats2half2_rn(a, b);
    return __builtin_bit_cast(unsigned int, h);
}
DEVINL float sigmoidf_(float x) { return 1.0f / (1.0f + __expf(-x)); }
DEVINL float tanhf_(float x) { return 2.0f / (1.0f + __expf(-2.0f * x)) - 1.0f; }

// s_tile u32-offset map (weights overlay; row_tile overwrites them after phase 0)
enum {
    O_PE1 = 0,        // [64][12]  pe_w1^T pairs (21 pad 24)
    O_PE2 = 768,      // [64][32]  pe_w2^T pairs
    O_EE1 = 2816,     // [32][8]   ee_w1^T pairs (13 pad 16)
    O_EE2 = 3072,     // [16][16]  ee_w2^T pairs
    O_CB1 = 3328,     // [128][32] cb_w1^T pairs (63 pad 64)
    O_CB2 = 7424,     // [64][64]  cb_w2^T pairs
    O_BIAS = 11520    // 400 floats: pe_b1(64) pe_b2(64) ee_b1(32) ee_b2(16) cb_b1(128) cb_b2(64) role(32)
};

__global__ __launch_bounds__(256) __attribute__((amdgpu_waves_per_eu(2, 2)))
void k_fused(
    const float* __restrict__ self_obs, const float* __restrict__ tm_obs,
    const float* __restrict__ en_obs, const float* __restrict__ cp_obs,
    const int* __restrict__ role_ids,
    const float* __restrict__ pe_w1, const float* __restrict__ pe_b1,
    const float* __restrict__ pe_w2, const float* __restrict__ pe_b2,
    const float* __restrict__ role_emb,
    const float* __restrict__ ee_w1, const float* __restrict__ ee_b1,
    const float* __restrict__ ee_w2, const float* __restrict__ ee_b2,
    const float* __restrict__ cb_w1, const float* __restrict__ cb_b1,
    const float* __restrict__ cb_w2, const float* __restrict__ cb_b2,
    const float* __restrict__ ih_w, const float* __restrict__ ih_b,
    const float* __restrict__ hh_w, const float* __restrict__ hh_b,
    const float* __restrict__ th_w, const float* __restrict__ th_b,
    const float* __restrict__ an_w, const float* __restrict__ an_b,
    const float* __restrict__ sh_w, const float* __restrict__ sh_b,
    const float* __restrict__ bo_w, const float* __restrict__ bo_b,
    const float* __restrict__ logstd, float* __restrict__ out)
{
    __shared__ __align__(16) unsigned int s_tile[Sn * 64];  // 64 KB: weights, then row tile
    __shared__ __align__(16) unsigned int s_h32[32];        // h as f16 pairs
    __shared__ float s_g[192];
    __shared__ unsigned int s_hw[192];
    __shared__ float s_hb[8];

    const int t = threadIdx.x;
    const int b = blockIdx.x;

    // ---------------- weight staging (f32 -> f16 pairs, transposed+padded) ----------------
    for (int i = t; i < 768; i += 256) {
        int o = i / 12, m = i % 12, k0 = 2 * m, k1 = k0 + 1;
        float a = (k0 < 21) ? pe_w1[k0 * 64 + o] : 0.f;
        float c = (k1 < 21) ? pe_w1[k1 * 64 + o] : 0.f;
        s_tile[O_PE1 + i] = packh2(a, c);
    }
    for (int i = t; i < 2048; i += 256) {
        int o = i >> 5, m = i & 31;
        s_tile[O_PE2 + i] = packh2(pe_w2[(2 * m) * 64 + o], pe_w2[(2 * m + 1) * 64 + o]);
    }
    {
        int i = t;  // 256 elems, one pass
        int o = i >> 3, m = i & 7, k0 = 2 * m, k1 = k0 + 1;
        float a = (k0 < 13) ? ee_w1[k0 * 32 + o] : 0.f;
        float c = (k1 < 13) ? ee_w1[k1 * 32 + o] : 0.f;
        s_tile[O_EE1 + i] = packh2(a, c);
    }
    {
        int i = t;
        int o = i >> 4, m = i & 15;
        s_tile[O_EE2 + i] = packh2(ee_w2[(2 * m) * 16 + o], ee_w2[(2 * m + 1) * 16 + o]);
    }
    for (int i = t; i < 4096; i += 256) {
        int o = i >> 5, m = i & 31, k0 = 2 * m, k1 = k0 + 1;
        float a = (k0 < 63) ? cb_w1[k0 * 128 + o] : 0.f;
        float c = (k1 < 63) ? cb_w1[k1 * 128 + o] : 0.f;
        s_tile[O_CB1 + i] = packh2(a, c);
    }
    for (int i = t; i < 4096; i += 256) {
        int o = i >> 6, m = i & 63;
        s_tile[O_CB2 + i] = packh2(cb_w2[(2 * m) * 64 + o], cb_w2[(2 * m + 1) * 64 + o]);
    }
    float* bias = (float*)(s_tile + O_BIAS);
    if (t < 64) bias[t] = pe_b1[t];
    if (t < 64) bias[64 + t] = pe_b2[t];
    if (t < 32) bias[128 + t] = ee_b1[t];
    if (t < 16) bias[160 + t] = ee_b2[t];
    if (t < 128) bias[176 + t] = cb_b1[t];
    if (t < 64) bias[304 + t] = cb_b2[t];
    if (t < 32) bias[368 + t] = role_emb[t];
    // head weights (persistent tail region)
    if (t < 32)        s_hw[t]        = packh2(th_w[2 * t], th_w[2 * t + 1]);
    else if (t < 64)  { int m = t - 32;  s_hw[32 + m]  = packh2(an_w[2 * m], an_w[2 * m + 1]); }
    else if (t < 96)  { int m = t - 64;  s_hw[64 + m]  = packh2(sh_w[4 * m], sh_w[4 * m + 2]); }
    else if (t < 128) { int m = t - 96;  s_hw[96 + m]  = packh2(sh_w[4 * m + 1], sh_w[4 * m + 3]); }
    else if (t < 160) { int m = t - 128; s_hw[128 + m] = packh2(bo_w[4 * m], bo_w[4 * m + 2]); }
    else if (t < 192) { int m = t - 160; s_hw[160 + m] = packh2(bo_w[4 * m + 1], bo_w[4 * m + 3]); }
    if (t == 0) {
        s_hb[0] = th_b[0]; s_hb[1] = an_b[0];
        s_hb[2] = sh_b[0]; s_hb[3] = sh_b[1];
        s_hb[4] = bo_b[0]; s_hb[5] = bo_b[1];
        s_hb[6] = fmaxf(__expf(logstd[0]), 0.05f);
        s_hb[7] = fmaxf(__expf(logstd[1]), 0.05f);
    }
    if (t < 32) s_h32[t] = 0u;  // h0 = 0 (f16 pairs)
    __syncthreads();

    // ---------------- phase 0: encoders, thread t handles step s=t ----------------
    {
        const long long row = (long long)b * Sn + t;
        // entity encoders: teammate -> lat[0..15], enemy max -> lat[16..31]
        float lat[32];
        #pragma unroll 1
        for (int src = 0; src < 3; src++) {
            const float* xp = (src == 0) ? (tm_obs + row * 13) : (en_obs + row * 26 + (src - 1) * 13);
            unsigned int xpr[8];
            #pragma unroll
            for (int m = 0; m < 8; m++) {
                int k0 = 2 * m, k1 = k0 + 1;
                xpr[m] = packh2((k0 < 13) ? xp[k0] : 0.f, (k1 < 13) ? xp[k1] : 0.f);
            }
            unsigned int e1[16];
            #pragma unroll
            for (int o2 = 0; o2 < 16; o2++) {
                float a0 = bias[128 + 2 * o2], a1 = bias[128 + 2 * o2 + 1];
                const unsigned int* w0 = s_tile + O_EE1 + (2 * o2) * 8;
                #pragma unroll
                for (int m = 0; m < 8; m++) { a0 = dot2(xpr[m], w0[m], a0); a1 = dot2(xpr[m], w0[8 + m], a1); }
                e1[o2] = packh2(fmaxf(a0, 0.f), fmaxf(a1, 0.f));
            }
            #pragma unroll
            for (int o = 0; o < 16; o++) {
                float a0 = bias[160 + o];
                const unsigned int* w0 = s_tile + O_EE2 + o * 16;
                #pragma unroll
                for (int m = 0; m < 16; m++) a0 = dot2(e1[m], w0[m], a0);
                if (src == 0) lat[o] = a0;                                  // teammate
                else if (src == 1) lat[16 + o] = a0;                        // enemy 0
                else lat[16 + o] = fmaxf(lat[16 + o], a0);                  // enemy 1 (max)
            }
        }
        // command input pack: self(15) | tm(16) | en(16) | role(16) = 63 (pad 64)
        unsigned int cpp[32];
        {
            const float* sp = self_obs + row * 15;
            const int rid = role_ids[row];
            const float* rvec = bias + 368 + rid * 16;
            #pragma unroll
            for (int m = 0; m < 32; m++) {
                int k0 = 2 * m, k1 = k0 + 1;
                float a = (k0 < 15) ? sp[k0] : (k0 < 31) ? lat[k0 - 15] : (k0 < 47) ? lat[16 + k0 - 31] : rvec[k0 - 47];
                float c = (k1 < 15) ? sp[k1] : (k1 < 31) ? lat[k1 - 15] : (k1 < 47) ? lat[16 + k1 - 31]
                                                                       : (k1 < 63) ? rvec[k1 - 47] : 0.f;
                cpp[m] = packh2(a, c);
            }
        }
        // cmd L1 (63->128 relu)
        unsigned int c1[64];
        #pragma unroll
        for (int o2 = 0; o2 < 64; o2++) {
            float a0 = bias[176 + 2 * o2], a1 = bias[176 + 2 * o2 + 1];
            const unsigned int* w0 = s_tile + O_CB1 + (2 * o2) * 32;
            #pragma unroll
            for (int m = 0; m < 32; m++) { a0 = dot2(cpp[m], w0[m], a0); a1 = dot2(cpp[m], w0[32 + m], a1); }
            c1[o2] = packh2(fmaxf(a0, 0.f), fmaxf(a1, 0.f));
        }
        // cmd L2 (128->64 relu) -> resc
        unsigned int resc[32];
        #pragma unroll
        for (int o2 = 0; o2 < 32; o2++) {
            float a0 = bias[304 + 2 * o2], a1 = bias[304 + 2 * o2 + 1];
            const unsigned int* w0 = s_tile + O_CB2 + (2 * o2) * 64;
            #pragma unroll
            for (int m = 0; m < 64; m++) { a0 = dot2(c1[m], w0[m], a0); a1 = dot2(c1[m], w0[64 + m], a1); }
            resc[o2] = packh2(fmaxf(a0, 0.f), fmaxf(a1, 0.f));
        }
        // pilot: input pack (reload self/cp)
        unsigned int inp[12];
        {
            const float* sp = self_obs + row * 15;
            const float* cp = cp_obs + row * 6;
            #pragma unroll
            for (int m = 0; m < 12; m++) {
                int k0 = 2 * m, k1 = k0 + 1;
                float a = (k0 < 15) ? sp[k0] : ((k0 < 21) ? cp[k0 - 15] : 0.f);
                float c = (k1 < 15) ? sp[k1] : ((k1 < 21) ? cp[k1 - 15] : 0.f);
                inp[m] = packh2(a, c);
            }
        }
        // pilot L1 (21->64 relu)
        unsigned int r1p[32];
        #pragma unroll
        for (int o2 = 0; o2 < 32; o2++) {
            float a0 = bias[2 * o2], a1 = bias[2 * o2 + 1];
            const unsigned int* w0 = s_tile + O_PE1 + (2 * o2) * 12;
            #pragma unroll
            for (int m = 0; m < 12; m++) { a0 = dot2(inp[m], w0[m], a0); a1 = dot2(inp[m], w0[12 + m], a1); }
            r1p[o2] = packh2(fmaxf(a0, 0.f), fmaxf(a1, 0.f));
        }
        // pilot L2 (64->64 relu) -> resp
        unsigned int resp[32];
        #pragma unroll
        for (int o2 = 0; o2 < 32; o2++) {
            float a0 = bias[64 + 2 * o2], a1 = bias[64 + 2 * o2 + 1];
            const unsigned int* w0 = s_tile + O_PE2 + (2 * o2) * 32;
            #pragma unroll
            for (int m = 0; m < 32; m++) { a0 = dot2(r1p[m], w0[m], a0); a1 = dot2(r1p[m], w0[32 + m], a1); }
            resp[o2] = packh2(fmaxf(a0, 0.f), fmaxf(a1, 0.f));
        }
        __syncthreads();  // all phase-0 reads of weights done
        // row tile overwrites weights: [pilot(32 u32) | cmd(32 u32)], vectorized
        uint4* rt4 = reinterpret_cast<uint4*>(s_tile + t * 64);
        #pragma unroll
        for (int q = 0; q < 8; q++)
            rt4[q] = make_uint4(resp[4 * q], resp[4 * q + 1], resp[4 * q + 2], resp[4 * q + 3]);
        #pragma unroll
        for (int q = 0; q < 8; q++)
            rt4[8 + q] = make_uint4(resc[4 * q], resc[4 * q + 1], resc[4 * q + 2], resc[4 * q + 3]);
    }

    // LSTM weight columns into registers (f16 pairs)
    unsigned int wih[64], whh[32];
    #pragma unroll
    for (int m = 0; m < 64; m++) wih[m] = packh2(ih_w[(2 * m) * 256 + t], ih_w[(2 * m + 1) * 256 + t]);
    #pragma unroll
    for (int m = 0; m < 32; m++) whh[m] = packh2(hh_w[(2 * m) * 256 + t], hh_w[(2 * m + 1) * 256 + t]);
    const float bias_t = ih_b[t] + hh_b[t];
    __syncthreads();  // row tile ready

    // ---------------- LSTM over S (branch-light loop) ----------------
    const int grp = t >> 6;
    const int u = t & 63;
    float c = 0.f, h = 0.f, i_act = 0.f;
    #pragma unroll 1
    for (int s = 0; s < Sn; s++) {
        float acc = bias_t;
        const uint4* rq = reinterpret_cast<const uint4*>(s_tile + s * 64);
        #pragma unroll
        for (int q = 0; q < 16; q++) {
            uint4 rv = rq[q];
            acc = dot2(rv.x, wih[4 * q + 0], acc);
            acc = dot2(rv.y, wih[4 * q + 1], acc);
            acc = dot2(rv.z, wih[4 * q + 2], acc);
            acc = dot2(rv.w, wih[4 * q + 3], acc);
        }
        const uint4* hq = reinterpret_cast<const uint4*>(s_h32);
        #pragma unroll
        for (int q = 0; q < 8; q++) {
            uint4 hv = hq[q];
            acc = dot2(hv.x, whh[4 * q + 0], acc);
            acc = dot2(hv.y, whh[4 * q + 1], acc);
            acc = dot2(hv.z, whh[4 * q + 2], acc);
            acc = dot2(hv.w, whh[4 * q + 3], acc);
        }
        float act = (grp == 2) ? tanhf_(acc) : sigmoidf_(acc);
        if (grp == 0) i_act = act; else s_g[t - 64] = act;
        __syncthreads();
        if (t < 64) {
            float f_ = s_g[u], g_ = s_g[64 + u], o_ = s_g[128 + u];
            c = f_ * c + i_act * g_;
            h = o_ * tanhf_(c);
            float hnext = __shfl_down(h, 1);
            if ((u & 1) == 0) {
                unsigned int hp = packh2(h, hnext);
                s_h32[u >> 1] = hp;                                   // for next step's hh-dot
                s_tile[s * 64 + (((u >> 1) + s) & 31)] = hp;          // h history, swizzled (row s is dead)
            }
        }
        __syncthreads();
    }

    // ---------------- heads for all steps (from h history in tile) ----------------
    {
        const int w = t >> 6, l = t & 63;
        const int m0 = (l & 7) * 4;
        const int j0 = l & 7;
        #pragma unroll 1
        for (int p = 0; p < 8; p++) {
            int s = w * 64 + p * 8 + (l >> 3);
            float ath = 0.f, aan = 0.f, as0 = 0.f, as1 = 0.f, ab0 = 0.f, ab1 = 0.f;
            #pragma unroll
            for (int j = 0; j < 4; j++) {
                int m = m0 + j;
                unsigned int hv = s_tile[s * 64 + ((m + s) & 31)];
                ath = dot2(hv, s_hw[m], ath);
                aan = dot2(hv, s_hw[32 + m], aan);
                as0 = dot2(hv, s_hw[64 + m], as0);
                as1 = dot2(hv, s_hw[96 + m], as1);
                ab0 = dot2(hv, s_hw[128 + m], ab0);
                ab1 = dot2(hv, s_hw[160 + m], ab1);
            }
            #pragma unroll
            for (int d = 1; d < 8; d <<= 1) {
                ath += __shfl_xor(ath, d); aan += __shfl_xor(aan, d);
                as0 += __shfl_xor(as0, d); as1 += __shfl_xor(as1, d);
                ab0 += __shfl_xor(ab0, d); ab1 += __shfl_xor(ab1, d);
            }
            long long row = (long long)b * Sn + s;
            if (j0 == 0)      out[row] = sigmoidf_(ath + s_hb[0]);
            else if (j0 == 1) out[BSn + row] = tanhf_(aan + s_hb[1]);
            else if (j0 == 2) out[2 * BSn + 2 * row] = s_hb[6];
            else if (j0 == 3) out[2 * BSn + 2 * row + 1] = s_hb[7];
            else if (j0 == 4) out[4 * BSn + 2 * row] = as0 + s_hb[2];
            else if (j0 == 5) out[4 * BSn + 2 * row + 1] = as1 + s_hb[3];
            else if (j0 == 6) out[6 * BSn + 2 * row] = ab0 + s_hb[4];
            else              out[6 * BSn + 2 * row + 1] = ab1 + s_hb[5];
        }
    }

    if (t < 64) {
        float* hn = out + 8 * BSn;
        float* cn = hn + (long long)Bn * 64;
        hn[(long long)b * 64 + u] = h;
        cn[(long long)b * 64 + u] = c;
    }
}

extern "C" void kernel_launch(void* const* d_in, const int* in_sizes, int n_in,
                              void* d_out, int out_size, void* d_ws, size_t ws_size,
                              hipStream_t stream)
{
    (void)in_sizes; (void)n_in; (void)out_size; (void)d_ws; (void)ws_size;
    k_fused<<<Bn, 256, 0, stream>>>(
        (const float*)d_in[0], (const float*)d_in[1], (const float*)d_in[2],
        (const float*)d_in[3], (const int*)d_in[4],
        (const float*)d_in[5], (const float*)d_in[6], (const float*)d_in[7], (const float*)d_in[8],
        (const float*)d_in[9],
        (const float*)d_in[10], (const float*)d_in[11], (const float*)d_in[12], (const float*)d_in[13],
        (const float*)d_in[14], (const float*)d_in[15], (const float*)d_in[16], (const float*)d_in[17],
        (const float*)d_in[18], (const float*)d_in[19], (const float*)d_in[20], (const float*)d_in[21],
        (const float*)d_in[22], (const float*)d_in[23], (const float*)d_in[24], (const float*)d_in[25],
        (const float*)d_in[26], (const float*)d_in[27], (const float*)d_in[28], (const float*)d_in[29],
        (const float*)d_in[30], (float*)d_out);
}